// Round 4
// baseline (9111.448 us; speedup 1.0000x reference)
//
#include <hip/hip_runtime.h>
#include <stdint.h>

// R8: 2 waves/SIMD (from R7's 7156 us; R5 7774). R7 post-mortem: stall floor
// ~12.5k cy/step barely moved from R5's ~10.8k despite halved compute -> the
// bottleneck is 1 wave/SIMD exposing every latency serially. The N-split's
// real payoff: per-wave weights now fit in 144 VGPR -> a 512-thread block
// (8 waves, 2/SIMD, 256-VGPR cap) no longer spills (R3's failure was the
// full 288-VGPR set). Each wave owns one 16-col j-tile x 4 gates.
//  - exchange mechanism UNCHANGED from R7 (relaxed system-scope u32, flag
//    after barrier C, parity ping-pong) -- verified correct.
//  - own-chunk MFMAs issue BEFORE the partner poll (cover + skew absorb).
//  - bias hoisted to registers (bb[4], per-thread constant).
// Failure signature: dur >= 7 ms => VGPR spill (shed afh/phf to LDS).

#define B_TOTAL   1024
#define H_DIM     256
#define F_WARM    32
#define F_AUTO    24
#define O_DIM     8
#define T_WARM    512
#define T_TOTAL   1024
#define N4H       1024
#define A_STR     168   // x(32)+h(128)+pad(8): 336 B/row, 16B-aligned

typedef __attribute__((ext_vector_type(8))) short short8;
typedef __attribute__((ext_vector_type(4))) float float4v;

#define GLOBAL_AS __attribute__((address_space(1)))
#define LDS_AS    __attribute__((address_space(3)))

__device__ __forceinline__ short f2bf(float x) {
    union { float f; uint32_t u; } v; v.f = x;
    uint32_t r = v.u + 0x7FFFu + ((v.u >> 16) & 1u);   // RNE
    return (short)(r >> 16);
}
__device__ __forceinline__ float sigmoid_(float x) {
    const float e = __expf(-x);
    return __builtin_amdgcn_rcpf(1.0f + e);
}
__device__ __forceinline__ float tanh_(float x) {
    const float e = __expf(-2.0f * fabsf(x));
    const float t = (1.0f - e) * __builtin_amdgcn_rcpf(1.0f + e);
    return x >= 0.0f ? t : -t;
}

__global__ __launch_bounds__(512, 2)
void lstm_pair(const float* __restrict__ c0, const float* __restrict__ h0,
               const float* __restrict__ warm, const float* __restrict__ autoin,
               const float* __restrict__ W_ih, const float* __restrict__ W_hh,
               const float* __restrict__ bvec, const float* __restrict__ W_out,
               const float* __restrict__ b_out, float* __restrict__ out,
               unsigned short* __restrict__ ws)
{
    const int tid  = threadIdx.x;
    const int w    = tid >> 6;        // wave 0..7 -> own h-units [w*16, +16)
    const int l    = tid & 63;
    const int n16  = l & 15;          // MFMA n / A row (m)
    const int kg   = l >> 4;          // k-group 0..3
    const int bid  = blockIdx.x;
    const int half = bid >> 6;        // N-half: h-units [half*128, +128)
    const int row0 = (bid & 63) * 16; // batch rows
    const int hb   = half * 128;      // own h base (global h index)
    const int qb   = 128 - hb;        // partner h base
    const int cl   = w * 16 + n16;    // own local col (0..127)

    uint32_t* myflag = (uint32_t*)((char*)ws + (size_t)bid * 64);
    uint32_t* pflag  = (uint32_t*)((char*)ws + (size_t)(bid ^ 64) * 64);
    uint32_t* obuf32 = (uint32_t*)((char*)ws + 8192) + (size_t)bid * 2048;
    uint32_t* pbuf32 = (uint32_t*)((char*)ws + 8192) + (size_t)(bid ^ 64) * 2048;

    __shared__ __align__(16) short Alds[16 * A_STR];    // [x(32) | own h(128) | pad]
    __shared__ __align__(16) unsigned short wsWl[4096]; // W_out MFMA B-frags
    __shared__ float biasL[512];                        // own 4 gates x 128
    __shared__ __align__(16) float xstage[512];         // x_{t+1} prefetch

    // ---- W_out frags -> LDS ----
    for (int idx = tid; idx < 4096; idx += 512) {
        const int i = idx & 7, lane = (idx >> 3) & 63, kk = idx >> 9;
        const int k = kk * 32 + (lane >> 4) * 8 + i;
        const int n = lane & 15;
        wsWl[idx] = (unsigned short)((n < O_DIM) ? f2bf(W_out[k * O_DIM + n]) : (short)0);
    }
    // ---- bias: own 512 cols, layout [g][128] ----
    {
        const int g = tid >> 7, loc = tid & 127;
        biasL[tid] = bvec[g * 256 + hb + loc];
    }

    // ---- register weights: 36 frags = 144 VGPR (compile-time indexed) ----
    short8 bwx[4];          // x chunk (W_ih rows 0..31)
    short8 bwo[4][4];       // own-h chunks c=0..3
    short8 bwp[4][4];       // partner-h chunks
    #pragma unroll
    for (int g = 0; g < 4; ++g) {
        const int col = g * 256 + hb + cl;
        {
            short8 f;
            #pragma unroll
            for (int i = 0; i < 8; ++i)
                f[i] = f2bf(W_ih[(kg * 8 + i) * N4H + col]);
            bwx[g] = f;
        }
        #pragma unroll
        for (int c = 0; c < 4; ++c) {
            short8 f, p;
            #pragma unroll
            for (int i = 0; i < 8; ++i) {
                const int kr = c * 32 + kg * 8 + i;
                f[i] = f2bf(W_hh[(hb + kr) * N4H + col]);
                p[i] = f2bf(W_hh[(qb + kr) * N4H + col]);
            }
            bwo[c][g] = f;
            bwp[c][g] = p;
        }
    }

    const float bout = (w == 0 && n16 < O_DIM) ? b_out[n16] : 0.0f;

    // ---- c state: rows kg*4+r, own col hb+cl ----
    float creg[4];
    #pragma unroll
    for (int r = 0; r < 4; ++r)
        creg[r] = c0[(size_t)(row0 + kg * 4 + r) * H_DIM + (hb + cl)];

    // ---- initial A: x_0 + own h0 ----
    {
        const int r = tid >> 5, cx = tid & 31;
        Alds[r * A_STR + cx] =
            f2bf(warm[(size_t)(row0 + r) * (T_WARM * F_WARM) + cx]);   // t=0
    }
    #pragma unroll
    for (int e = 0; e < 4; ++e) {
        const int idx = tid + e * 512;
        const int r = idx >> 7, c = idx & 127;
        Alds[r * A_STR + F_WARM + c] = f2bf(h0[(size_t)(row0 + r) * H_DIM + hb + c]);
    }
    // ---- phf init: partner h0 frags ----
    short8 phf[4];
    #pragma unroll
    for (int c = 0; c < 4; ++c) {
        short8 f;
        #pragma unroll
        for (int i = 0; i < 8; ++i)
            f[i] = f2bf(h0[(size_t)(row0 + n16) * H_DIM + qb + c * 32 + kg * 8 + i]);
        phf[c] = f;
    }

    __syncthreads();                            // prologue LDS published
    float bb[4];
    #pragma unroll
    for (int g = 0; g < 4; ++g) bb[g] = biasL[g * 128 + cl];

    const short* abase = &Alds[n16 * A_STR + kg * 8];
    const short8* wsW8 = (const short8*)wsWl;
    const int shx = (n16 & 1) * 16;             // row half in u32 word

    for (int t = 0; t < T_TOTAL; ++t) {
        __syncthreads();                        // A: Alds(h_{t-1}, x_t) ready

        // ---- async prefetch x_{t+1} (1 elem/thread) ----
        const int tn = t + 1;
        if (tn < T_TOTAL) {
            const int r = tid >> 5, cx = tid & 31;
            const float* gp;
            if (tn < T_WARM)
                gp = &warm[(size_t)(row0 + r) * (T_WARM * F_WARM)
                           + (size_t)tn * F_WARM + cx];
            else
                gp = &autoin[(size_t)(row0 + r) * (T_WARM * F_AUTO)
                             + (size_t)(tn - T_WARM) * F_AUTO
                             + ((cx < F_AUTO) ? cx : 0)];
            __builtin_amdgcn_global_load_lds(
                (const GLOBAL_AS void*)gp,
                (LDS_AS void*)&xstage[w * 64], 4, 0, 0);
        }

        // ---- own A-frags ----
        short8 afh[4];
        #pragma unroll
        for (int c = 0; c < 4; ++c)
            afh[c] = *(const short8*)(abase + 32 + c * 32);

        // ---- own-chunk MFMAs FIRST (no phf dependency; covers poll) ----
        float4v acc[4];
        #pragma unroll
        for (int g = 0; g < 4; ++g)
            acc[g] = (float4v){0.f, 0.f, 0.f, 0.f};
        #pragma unroll
        for (int c = 0; c < 4; ++c)
            #pragma unroll
            for (int g = 0; g < 4; ++g)
                acc[g] = __builtin_amdgcn_mfma_f32_16x16x32_bf16(
                             afh[c], bwo[c][g], acc[g], 0, 0, 0);

        // ---- poll partner flag >= t, then phf loads (h_{t-1}) ----
        if (t >= 1) {
            while (__hip_atomic_load(pflag, __ATOMIC_RELAXED,
                                     __HIP_MEMORY_SCOPE_SYSTEM) < (uint32_t)t)
                __builtin_amdgcn_s_sleep(1);
            asm volatile("" ::: "memory");
            const uint32_t* pb = pbuf32 + ((t - 1) & 1) * 1024;
            #pragma unroll
            for (int c = 0; c < 4; ++c) {
                uint32_t wv[8];
                #pragma unroll
                for (int i = 0; i < 8; ++i)
                    wv[i] = __hip_atomic_load(&pb[(c * 32 + kg * 8 + i) * 8 + (n16 >> 1)],
                                              __ATOMIC_RELAXED, __HIP_MEMORY_SCOPE_SYSTEM);
                short8 f;
                #pragma unroll
                for (int i = 0; i < 8; ++i)
                    f[i] = (short)((wv[i] >> shx) & 0xFFFFu);
                phf[c] = f;
            }
        }

        // ---- partner-chunk MFMAs ----
        #pragma unroll
        for (int c = 0; c < 4; ++c)
            #pragma unroll
            for (int g = 0; g < 4; ++g)
                acc[g] = __builtin_amdgcn_mfma_f32_16x16x32_bf16(
                             phf[c], bwp[c][g], acc[g], 0, 0, 0);

        // ---- wave0: y_{t-1} from afh + phf ----
        if (w == 0 && t >= 1) {
            float4v ya = (float4v){bout, bout, bout, bout};
            #pragma unroll
            for (int c = 0; c < 4; ++c)
                ya = __builtin_amdgcn_mfma_f32_16x16x32_bf16(
                         afh[c], wsW8[(hb / 32 + c) * 64 + l], ya, 0, 0, 0);
            #pragma unroll
            for (int c = 0; c < 4; ++c)
                ya = __builtin_amdgcn_mfma_f32_16x16x32_bf16(
                         phf[c], wsW8[(qb / 32 + c) * 64 + l], ya, 0, 0, 0);
            if (n16 < O_DIM) {
                if (half == 0) {
                    #pragma unroll
                    for (int r = 0; r < 4; ++r)
                        out[(size_t)(row0 + kg * 4 + r) * (T_TOTAL * O_DIM)
                            + (size_t)(t - 1) * O_DIM + n16] = ya[r];
                }
                if (t >= T_WARM) {                      // feedback cols [24,32)
                    #pragma unroll
                    for (int r = 0; r < 4; ++r)
                        Alds[(kg * 4 + r) * A_STR + F_AUTO + n16] = f2bf(ya[r]);
                }
            }
        }

        if (t >= T_WARM) __syncthreads();       // B: feedback cols ready

        {
            const short8 af = *(const short8*)(abase);  // x chunk (+feedback)
            #pragma unroll
            for (int g = 0; g < 4; ++g)
                acc[g] = __builtin_amdgcn_mfma_f32_16x16x32_bf16(
                             af, bwx[g], acc[g], 0, 0, 0);
        }

        // ---- gates + c/h update (4 h-vals/thread) ----
        uint32_t hp[2];
        {
            uint32_t u0 = 0, u1 = 0;
            #pragma unroll
            for (int r = 0; r < 4; ++r) {
                const float ig = sigmoid_(acc[0][r] + bb[0]);
                const float fg = sigmoid_(acc[1][r] + bb[1]);
                const float gg = tanh_(acc[2][r] + bb[2]);
                const float og = sigmoid_(acc[3][r] + bb[3]);
                const float cc = fg * creg[r] + ig * gg;
                creg[r] = cc;
                const float hh = og * tanh_(cc);
                const uint32_t hbv = (uint32_t)(uint16_t)f2bf(hh);
                if (r == 0) u0 = hbv;       else if (r == 1) u0 |= hbv << 16;
                else if (r == 2) u1 = hbv;  else              u1 |= hbv << 16;
            }
            hp[0] = u0; hp[1] = u1;
        }

        // ---- publish h_t: u32 row-pair words, relaxed system-scope ----
        {
            uint32_t* ob = obuf32 + (t & 1) * 1024;
            __hip_atomic_store(&ob[cl * 8 + kg * 2 + 0], hp[0],
                               __ATOMIC_RELAXED, __HIP_MEMORY_SCOPE_SYSTEM);
            __hip_atomic_store(&ob[cl * 8 + kg * 2 + 1], hp[1],
                               __ATOMIC_RELAXED, __HIP_MEMORY_SCOPE_SYSTEM);
        }

        __syncthreads();                        // C: vmcnt(0) drains publishes

        if (tid == 0)                           // release: after-barrier flag
            __hip_atomic_store(myflag, (uint32_t)(t + 1),
                               __ATOMIC_RELAXED, __HIP_MEMORY_SCOPE_SYSTEM);

        // ---- write own h_t into Alds ----
        {
            const int ac = F_WARM + cl;
            Alds[(kg * 4 + 0) * A_STR + ac] = (short)(hp[0] & 0xFFFF);
            Alds[(kg * 4 + 1) * A_STR + ac] = (short)(hp[0] >> 16);
            Alds[(kg * 4 + 2) * A_STR + ac] = (short)(hp[1] & 0xFFFF);
            Alds[(kg * 4 + 3) * A_STR + ac] = (short)(hp[1] >> 16);
        }
        // ---- commit prefetched x_{t+1} ----
        if (tn < T_TOTAL) {
            const int r = tid >> 5, cx = tid & 31;
            if (tn < T_WARM || cx < F_AUTO)
                Alds[r * A_STR + cx] = f2bf(xstage[tid]);
        }
        // loop-top barrier A publishes Alds(h_t, x_{t+1})
    }

    // ---- epilogue: y_{T-1} (wave0 only; needs partner h_{T-1}) ----
    __syncthreads();
    if (w == 0) {
        while (__hip_atomic_load(pflag, __ATOMIC_RELAXED,
                                 __HIP_MEMORY_SCOPE_SYSTEM) < (uint32_t)T_TOTAL)
            __builtin_amdgcn_s_sleep(1);
        asm volatile("" ::: "memory");
        const uint32_t* pb = pbuf32 + ((T_TOTAL - 1) & 1) * 1024;
        #pragma unroll
        for (int c = 0; c < 4; ++c) {
            uint32_t wv[8];
            #pragma unroll
            for (int i = 0; i < 8; ++i)
                wv[i] = __hip_atomic_load(&pb[(c * 32 + kg * 8 + i) * 8 + (n16 >> 1)],
                                          __ATOMIC_RELAXED, __HIP_MEMORY_SCOPE_SYSTEM);
            short8 f;
            #pragma unroll
            for (int i = 0; i < 8; ++i)
                f[i] = (short)((wv[i] >> shx) & 0xFFFFu);
            phf[c] = f;
        }
        float4v ya = (float4v){bout, bout, bout, bout};
        #pragma unroll
        for (int c = 0; c < 4; ++c)
            ya = __builtin_amdgcn_mfma_f32_16x16x32_bf16(
                     *(const short8*)(abase + 32 + c * 32),
                     wsW8[(hb / 32 + c) * 64 + l], ya, 0, 0, 0);
        #pragma unroll
        for (int c = 0; c < 4; ++c)
            ya = __builtin_amdgcn_mfma_f32_16x16x32_bf16(
                     phf[c], wsW8[(qb / 32 + c) * 64 + l], ya, 0, 0, 0);
        if (half == 0 && n16 < O_DIM) {
            #pragma unroll
            for (int r = 0; r < 4; ++r)
                out[(size_t)(row0 + kg * 4 + r) * (T_TOTAL * O_DIM)
                    + (size_t)(T_TOTAL - 1) * O_DIM + n16] = ya[r];
        }
    }
}

extern "C" void kernel_launch(void* const* d_in, const int* in_sizes, int n_in,
                              void* d_out, int out_size, void* d_ws, size_t ws_size,
                              hipStream_t stream) {
    (void)in_sizes; (void)n_in; (void)out_size; (void)ws_size;
    const float* c0   = (const float*)d_in[0];
    const float* h0   = (const float*)d_in[1];
    const float* warm = (const float*)d_in[2];
    const float* aut  = (const float*)d_in[3];
    const float* Wih  = (const float*)d_in[4];
    const float* Whh  = (const float*)d_in[5];
    const float* b    = (const float*)d_in[6];
    const float* Wout = (const float*)d_in[7];
    const float* bout = (const float*)d_in[8];
    float* out = (float*)d_out;
    unsigned short* ws = (unsigned short*)d_ws;
    // ws layout: [0,8KB) flags (64B/WG); [8KB,8KB+1MB) h-exchange ping-pong.
    hipMemsetAsync(d_ws, 0, 8192, stream);
    hipLaunchKernelGGL(lstm_pair, dim3(128), dim3(512), 0, stream,
                       c0, h0, warm, aut, Wih, Whh, b, Wout, bout, out, ws);
}

// Round 5
// 9068.194 us; speedup vs baseline: 1.0048x; 1.0048x over previous
//
#include <hip/hip_runtime.h>
#include <stdint.h>

// R9: R8 with the register budget FIXED (R8: 9111 us, R7: 7156 us).
// R8 post-mortem: __launch_bounds__(512, 2) made the allocator budget for
// 16 waves/CU -> 128 unified regs/wave; ~230 regs of per-wave state spilled
// (VGPR_Count=128, VALUBusy collapsed, bank conflicts 2x). The 2-waves/SIMD
// experiment never ran. R9 = identical kernel with __launch_bounds__(512, 1):
// 1 block/CU -> 8 waves -> 2 waves/SIMD -> 256 regs/wave (state fits, ~230).
// Theory: co-resident SIMD-mate covers LDS/UC/poll/exp stalls -> R7's
// ~12.5k cy/step exposed-stall floor roughly halves.
// Gate counter: VGPR_Count must read 256. dur predicted 4.5-5.8 ms.

#define B_TOTAL   1024
#define H_DIM     256
#define F_WARM    32
#define F_AUTO    24
#define O_DIM     8
#define T_WARM    512
#define T_TOTAL   1024
#define N4H       1024
#define A_STR     168   // x(32)+h(128)+pad(8): 336 B/row, 16B-aligned

typedef __attribute__((ext_vector_type(8))) short short8;
typedef __attribute__((ext_vector_type(4))) float float4v;

#define GLOBAL_AS __attribute__((address_space(1)))
#define LDS_AS    __attribute__((address_space(3)))

__device__ __forceinline__ short f2bf(float x) {
    union { float f; uint32_t u; } v; v.f = x;
    uint32_t r = v.u + 0x7FFFu + ((v.u >> 16) & 1u);   // RNE
    return (short)(r >> 16);
}
__device__ __forceinline__ float sigmoid_(float x) {
    const float e = __expf(-x);
    return __builtin_amdgcn_rcpf(1.0f + e);
}
__device__ __forceinline__ float tanh_(float x) {
    const float e = __expf(-2.0f * fabsf(x));
    const float t = (1.0f - e) * __builtin_amdgcn_rcpf(1.0f + e);
    return x >= 0.0f ? t : -t;
}

__global__ __launch_bounds__(512, 1)
void lstm_pair(const float* __restrict__ c0, const float* __restrict__ h0,
               const float* __restrict__ warm, const float* __restrict__ autoin,
               const float* __restrict__ W_ih, const float* __restrict__ W_hh,
               const float* __restrict__ bvec, const float* __restrict__ W_out,
               const float* __restrict__ b_out, float* __restrict__ out,
               unsigned short* __restrict__ ws)
{
    const int tid  = threadIdx.x;
    const int w    = tid >> 6;        // wave 0..7 -> own h-units [w*16, +16)
    const int l    = tid & 63;
    const int n16  = l & 15;          // MFMA n / A row (m)
    const int kg   = l >> 4;          // k-group 0..3
    const int bid  = blockIdx.x;
    const int half = bid >> 6;        // N-half: h-units [half*128, +128)
    const int row0 = (bid & 63) * 16; // batch rows
    const int hb   = half * 128;      // own h base (global h index)
    const int qb   = 128 - hb;        // partner h base
    const int cl   = w * 16 + n16;    // own local col (0..127)

    uint32_t* myflag = (uint32_t*)((char*)ws + (size_t)bid * 64);
    uint32_t* pflag  = (uint32_t*)((char*)ws + (size_t)(bid ^ 64) * 64);
    uint32_t* obuf32 = (uint32_t*)((char*)ws + 8192) + (size_t)bid * 2048;
    uint32_t* pbuf32 = (uint32_t*)((char*)ws + 8192) + (size_t)(bid ^ 64) * 2048;

    __shared__ __align__(16) short Alds[16 * A_STR];    // [x(32) | own h(128) | pad]
    __shared__ __align__(16) unsigned short wsWl[4096]; // W_out MFMA B-frags
    __shared__ float biasL[512];                        // own 4 gates x 128
    __shared__ __align__(16) float xstage[512];         // x_{t+1} prefetch

    // ---- W_out frags -> LDS ----
    for (int idx = tid; idx < 4096; idx += 512) {
        const int i = idx & 7, lane = (idx >> 3) & 63, kk = idx >> 9;
        const int k = kk * 32 + (lane >> 4) * 8 + i;
        const int n = lane & 15;
        wsWl[idx] = (unsigned short)((n < O_DIM) ? f2bf(W_out[k * O_DIM + n]) : (short)0);
    }
    // ---- bias: own 512 cols, layout [g][128] ----
    {
        const int g = tid >> 7, loc = tid & 127;
        biasL[tid] = bvec[g * 256 + hb + loc];
    }

    // ---- register weights: 36 frags = 144 VGPR (compile-time indexed) ----
    short8 bwx[4];          // x chunk (W_ih rows 0..31)
    short8 bwo[4][4];       // own-h chunks c=0..3
    short8 bwp[4][4];       // partner-h chunks
    #pragma unroll
    for (int g = 0; g < 4; ++g) {
        const int col = g * 256 + hb + cl;
        {
            short8 f;
            #pragma unroll
            for (int i = 0; i < 8; ++i)
                f[i] = f2bf(W_ih[(kg * 8 + i) * N4H + col]);
            bwx[g] = f;
        }
        #pragma unroll
        for (int c = 0; c < 4; ++c) {
            short8 f, p;
            #pragma unroll
            for (int i = 0; i < 8; ++i) {
                const int kr = c * 32 + kg * 8 + i;
                f[i] = f2bf(W_hh[(hb + kr) * N4H + col]);
                p[i] = f2bf(W_hh[(qb + kr) * N4H + col]);
            }
            bwo[c][g] = f;
            bwp[c][g] = p;
        }
    }

    const float bout = (w == 0 && n16 < O_DIM) ? b_out[n16] : 0.0f;

    // ---- c state: rows kg*4+r, own col hb+cl ----
    float creg[4];
    #pragma unroll
    for (int r = 0; r < 4; ++r)
        creg[r] = c0[(size_t)(row0 + kg * 4 + r) * H_DIM + (hb + cl)];

    // ---- initial A: x_0 + own h0 ----
    {
        const int r = tid >> 5, cx = tid & 31;
        Alds[r * A_STR + cx] =
            f2bf(warm[(size_t)(row0 + r) * (T_WARM * F_WARM) + cx]);   // t=0
    }
    #pragma unroll
    for (int e = 0; e < 4; ++e) {
        const int idx = tid + e * 512;
        const int r = idx >> 7, c = idx & 127;
        Alds[r * A_STR + F_WARM + c] = f2bf(h0[(size_t)(row0 + r) * H_DIM + hb + c]);
    }
    // ---- phf init: partner h0 frags ----
    short8 phf[4];
    #pragma unroll
    for (int c = 0; c < 4; ++c) {
        short8 f;
        #pragma unroll
        for (int i = 0; i < 8; ++i)
            f[i] = f2bf(h0[(size_t)(row0 + n16) * H_DIM + qb + c * 32 + kg * 8 + i]);
        phf[c] = f;
    }

    __syncthreads();                            // prologue LDS published
    float bb[4];
    #pragma unroll
    for (int g = 0; g < 4; ++g) bb[g] = biasL[g * 128 + cl];

    const short* abase = &Alds[n16 * A_STR + kg * 8];
    const short8* wsW8 = (const short8*)wsWl;
    const int shx = (n16 & 1) * 16;             // row half in u32 word

    for (int t = 0; t < T_TOTAL; ++t) {
        __syncthreads();                        // A: Alds(h_{t-1}, x_t) ready

        // ---- async prefetch x_{t+1} (1 elem/thread) ----
        const int tn = t + 1;
        if (tn < T_TOTAL) {
            const int r = tid >> 5, cx = tid & 31;
            const float* gp;
            if (tn < T_WARM)
                gp = &warm[(size_t)(row0 + r) * (T_WARM * F_WARM)
                           + (size_t)tn * F_WARM + cx];
            else
                gp = &autoin[(size_t)(row0 + r) * (T_WARM * F_AUTO)
                             + (size_t)(tn - T_WARM) * F_AUTO
                             + ((cx < F_AUTO) ? cx : 0)];
            __builtin_amdgcn_global_load_lds(
                (const GLOBAL_AS void*)gp,
                (LDS_AS void*)&xstage[w * 64], 4, 0, 0);
        }

        // ---- own A-frags ----
        short8 afh[4];
        #pragma unroll
        for (int c = 0; c < 4; ++c)
            afh[c] = *(const short8*)(abase + 32 + c * 32);

        // ---- own-chunk MFMAs FIRST (no phf dependency; covers poll) ----
        float4v acc[4];
        #pragma unroll
        for (int g = 0; g < 4; ++g)
            acc[g] = (float4v){0.f, 0.f, 0.f, 0.f};
        #pragma unroll
        for (int c = 0; c < 4; ++c)
            #pragma unroll
            for (int g = 0; g < 4; ++g)
                acc[g] = __builtin_amdgcn_mfma_f32_16x16x32_bf16(
                             afh[c], bwo[c][g], acc[g], 0, 0, 0);

        // ---- poll partner flag >= t, then phf loads (h_{t-1}) ----
        if (t >= 1) {
            while (__hip_atomic_load(pflag, __ATOMIC_RELAXED,
                                     __HIP_MEMORY_SCOPE_SYSTEM) < (uint32_t)t)
                __builtin_amdgcn_s_sleep(1);
            asm volatile("" ::: "memory");
            const uint32_t* pb = pbuf32 + ((t - 1) & 1) * 1024;
            #pragma unroll
            for (int c = 0; c < 4; ++c) {
                uint32_t wv[8];
                #pragma unroll
                for (int i = 0; i < 8; ++i)
                    wv[i] = __hip_atomic_load(&pb[(c * 32 + kg * 8 + i) * 8 + (n16 >> 1)],
                                              __ATOMIC_RELAXED, __HIP_MEMORY_SCOPE_SYSTEM);
                short8 f;
                #pragma unroll
                for (int i = 0; i < 8; ++i)
                    f[i] = (short)((wv[i] >> shx) & 0xFFFFu);
                phf[c] = f;
            }
        }

        // ---- partner-chunk MFMAs ----
        #pragma unroll
        for (int c = 0; c < 4; ++c)
            #pragma unroll
            for (int g = 0; g < 4; ++g)
                acc[g] = __builtin_amdgcn_mfma_f32_16x16x32_bf16(
                             phf[c], bwp[c][g], acc[g], 0, 0, 0);

        // ---- wave0: y_{t-1} from afh + phf ----
        if (w == 0 && t >= 1) {
            float4v ya = (float4v){bout, bout, bout, bout};
            #pragma unroll
            for (int c = 0; c < 4; ++c)
                ya = __builtin_amdgcn_mfma_f32_16x16x32_bf16(
                         afh[c], wsW8[(hb / 32 + c) * 64 + l], ya, 0, 0, 0);
            #pragma unroll
            for (int c = 0; c < 4; ++c)
                ya = __builtin_amdgcn_mfma_f32_16x16x32_bf16(
                         phf[c], wsW8[(qb / 32 + c) * 64 + l], ya, 0, 0, 0);
            if (n16 < O_DIM) {
                if (half == 0) {
                    #pragma unroll
                    for (int r = 0; r < 4; ++r)
                        out[(size_t)(row0 + kg * 4 + r) * (T_TOTAL * O_DIM)
                            + (size_t)(t - 1) * O_DIM + n16] = ya[r];
                }
                if (t >= T_WARM) {                      // feedback cols [24,32)
                    #pragma unroll
                    for (int r = 0; r < 4; ++r)
                        Alds[(kg * 4 + r) * A_STR + F_AUTO + n16] = f2bf(ya[r]);
                }
            }
        }

        if (t >= T_WARM) __syncthreads();       // B: feedback cols ready

        {
            const short8 af = *(const short8*)(abase);  // x chunk (+feedback)
            #pragma unroll
            for (int g = 0; g < 4; ++g)
                acc[g] = __builtin_amdgcn_mfma_f32_16x16x32_bf16(
                             af, bwx[g], acc[g], 0, 0, 0);
        }

        // ---- gates + c/h update (4 h-vals/thread) ----
        uint32_t hp[2];
        {
            uint32_t u0 = 0, u1 = 0;
            #pragma unroll
            for (int r = 0; r < 4; ++r) {
                const float ig = sigmoid_(acc[0][r] + bb[0]);
                const float fg = sigmoid_(acc[1][r] + bb[1]);
                const float gg = tanh_(acc[2][r] + bb[2]);
                const float og = sigmoid_(acc[3][r] + bb[3]);
                const float cc = fg * creg[r] + ig * gg;
                creg[r] = cc;
                const float hh = og * tanh_(cc);
                const uint32_t hbv = (uint32_t)(uint16_t)f2bf(hh);
                if (r == 0) u0 = hbv;       else if (r == 1) u0 |= hbv << 16;
                else if (r == 2) u1 = hbv;  else              u1 |= hbv << 16;
            }
            hp[0] = u0; hp[1] = u1;
        }

        // ---- publish h_t: u32 row-pair words, relaxed system-scope ----
        {
            uint32_t* ob = obuf32 + (t & 1) * 1024;
            __hip_atomic_store(&ob[cl * 8 + kg * 2 + 0], hp[0],
                               __ATOMIC_RELAXED, __HIP_MEMORY_SCOPE_SYSTEM);
            __hip_atomic_store(&ob[cl * 8 + kg * 2 + 1], hp[1],
                               __ATOMIC_RELAXED, __HIP_MEMORY_SCOPE_SYSTEM);
        }

        __syncthreads();                        // C: vmcnt(0) drains publishes

        if (tid == 0)                           // release: after-barrier flag
            __hip_atomic_store(myflag, (uint32_t)(t + 1),
                               __ATOMIC_RELAXED, __HIP_MEMORY_SCOPE_SYSTEM);

        // ---- write own h_t into Alds ----
        {
            const int ac = F_WARM + cl;
            Alds[(kg * 4 + 0) * A_STR + ac] = (short)(hp[0] & 0xFFFF);
            Alds[(kg * 4 + 1) * A_STR + ac] = (short)(hp[0] >> 16);
            Alds[(kg * 4 + 2) * A_STR + ac] = (short)(hp[1] & 0xFFFF);
            Alds[(kg * 4 + 3) * A_STR + ac] = (short)(hp[1] >> 16);
        }
        // ---- commit prefetched x_{t+1} ----
        if (tn < T_TOTAL) {
            const int r = tid >> 5, cx = tid & 31;
            if (tn < T_WARM || cx < F_AUTO)
                Alds[r * A_STR + cx] = f2bf(xstage[tid]);
        }
        // loop-top barrier A publishes Alds(h_t, x_{t+1})
    }

    // ---- epilogue: y_{T-1} (wave0 only; needs partner h_{T-1}) ----
    __syncthreads();
    if (w == 0) {
        while (__hip_atomic_load(pflag, __ATOMIC_RELAXED,
                                 __HIP_MEMORY_SCOPE_SYSTEM) < (uint32_t)T_TOTAL)
            __builtin_amdgcn_s_sleep(1);
        asm volatile("" ::: "memory");
        const uint32_t* pb = pbuf32 + ((T_TOTAL - 1) & 1) * 1024;
        #pragma unroll
        for (int c = 0; c < 4; ++c) {
            uint32_t wv[8];
            #pragma unroll
            for (int i = 0; i < 8; ++i)
                wv[i] = __hip_atomic_load(&pb[(c * 32 + kg * 8 + i) * 8 + (n16 >> 1)],
                                          __ATOMIC_RELAXED, __HIP_MEMORY_SCOPE_SYSTEM);
            short8 f;
            #pragma unroll
            for (int i = 0; i < 8; ++i)
                f[i] = (short)((wv[i] >> shx) & 0xFFFFu);
            phf[c] = f;
        }
        float4v ya = (float4v){bout, bout, bout, bout};
        #pragma unroll
        for (int c = 0; c < 4; ++c)
            ya = __builtin_amdgcn_mfma_f32_16x16x32_bf16(
                     *(const short8*)(abase + 32 + c * 32),
                     wsW8[(hb / 32 + c) * 64 + l], ya, 0, 0, 0);
        #pragma unroll
        for (int c = 0; c < 4; ++c)
            ya = __builtin_amdgcn_mfma_f32_16x16x32_bf16(
                     phf[c], wsW8[(qb / 32 + c) * 64 + l], ya, 0, 0, 0);
        if (half == 0 && n16 < O_DIM) {
            #pragma unroll
            for (int r = 0; r < 4; ++r)
                out[(size_t)(row0 + kg * 4 + r) * (T_TOTAL * O_DIM)
                    + (size_t)(T_TOTAL - 1) * O_DIM + n16] = ya[r];
        }
    }
}

extern "C" void kernel_launch(void* const* d_in, const int* in_sizes, int n_in,
                              void* d_out, int out_size, void* d_ws, size_t ws_size,
                              hipStream_t stream) {
    (void)in_sizes; (void)n_in; (void)out_size; (void)ws_size;
    const float* c0   = (const float*)d_in[0];
    const float* h0   = (const float*)d_in[1];
    const float* warm = (const float*)d_in[2];
    const float* aut  = (const float*)d_in[3];
    const float* Wih  = (const float*)d_in[4];
    const float* Whh  = (const float*)d_in[5];
    const float* b    = (const float*)d_in[6];
    const float* Wout = (const float*)d_in[7];
    const float* bout = (const float*)d_in[8];
    float* out = (float*)d_out;
    unsigned short* ws = (unsigned short*)d_ws;
    // ws layout: [0,8KB) flags (64B/WG); [8KB,8KB+1MB) h-exchange ping-pong.
    hipMemsetAsync(d_ws, 0, 8192, stream);
    hipLaunchKernelGGL(lstm_pair, dim3(128), dim3(512), 0, stream,
                       c0, h0, warm, aut, Wih, Whh, b, Wout, bout, out, ws);
}

// Round 6
// 5990.979 us; speedup vs baseline: 1.5209x; 1.5136x over previous
//
#include <hip/hip_runtime.h>
#include <stdint.h>

// R10: R7 + double-buffered A-tile => one fewer barrier/step (R7: 7156 us).
// R8/R9 post-mortem: VGPR_Count is arch-VGPRs (AGPRs hid the rest) -- the
// 2-waves/SIMD experiment ran and LOST 27%: intra-WG waves are barrier-
// phase-locked (stall at the same instants; no coverage) + 8-wave barrier
// skew + doubled LDS traffic. Reverted to 256-thread R7 structure.
// R10 changes (barrier-round-trip reduction):
//  - Abuf[2] ping-pong: step t reads buf[t&1] (x_t,h_{t-1}), writes h_t and
//    x_{t+1} into buf[(t+1)&1] -> barrier C deleted. Warm: 1 barrier/step
//    (was 2); auto: 2 (was 3). Publish drain moves to loop-top barrier A;
//    flag (h_{t-1} readable) stored by tid0 right after A.
//  - explicit s_waitcnt vmcnt(0) before xstage commit (was covered by C);
//    placed BEFORE the UC publishes are issued so it only drains the old
//    x-prefetch loads (cheap).
//  - v_cvt_pk_bf16_f32 for h bf16 pack (HW RNE, saves ~16 VALU/thread).
//  - half-1 skips the y-MFMA block during warm (y unused there).
// Decision rule: >=7.0ms => barriers aren't the stall mass -> R11 = LDS-flag
// phase-diverse intra-WG groups. In-range => stack R11 on this.

#define B_TOTAL   1024
#define H_DIM     256
#define F_WARM    32
#define F_AUTO    24
#define O_DIM     8
#define T_WARM    512
#define T_TOTAL   1024
#define N4H       1024
#define A_STR     168   // x(32)+h(128)+pad(8): 336 B/row, 16B-aligned

typedef __attribute__((ext_vector_type(8))) short short8;
typedef __attribute__((ext_vector_type(4))) float float4v;

#define GLOBAL_AS __attribute__((address_space(1)))
#define LDS_AS    __attribute__((address_space(3)))

__device__ __forceinline__ short f2bf(float x) {
    union { float f; uint32_t u; } v; v.f = x;
    uint32_t r = v.u + 0x7FFFu + ((v.u >> 16) & 1u);   // RNE
    return (short)(r >> 16);
}
__device__ __forceinline__ float sigmoid_(float x) {
    const float e = __expf(-x);
    return __builtin_amdgcn_rcpf(1.0f + e);
}
__device__ __forceinline__ float tanh_(float x) {
    const float e = __expf(-2.0f * fabsf(x));
    const float t = (1.0f - e) * __builtin_amdgcn_rcpf(1.0f + e);
    return x >= 0.0f ? t : -t;
}

__global__ __launch_bounds__(256, 1)
void lstm_pair(const float* __restrict__ c0, const float* __restrict__ h0,
               const float* __restrict__ warm, const float* __restrict__ autoin,
               const float* __restrict__ W_ih, const float* __restrict__ W_hh,
               const float* __restrict__ bvec, const float* __restrict__ W_out,
               const float* __restrict__ b_out, float* __restrict__ out,
               unsigned short* __restrict__ ws)
{
    const int tid  = threadIdx.x;
    const int w    = tid >> 6;        // wave 0..3 -> own h-units [w*32, +32)
    const int l    = tid & 63;
    const int n16  = l & 15;          // MFMA n / A row (m)
    const int kg   = l >> 4;          // k-group 0..3
    const int bid  = blockIdx.x;
    const int half = bid >> 6;        // N-half: h-units [half*128, +128)
    const int row0 = (bid & 63) * 16; // batch rows
    const int hb   = half * 128;      // own h base (global h index)
    const int qb   = 128 - hb;        // partner h base

    uint32_t* myflag = (uint32_t*)((char*)ws + (size_t)bid * 64);
    uint32_t* pflag  = (uint32_t*)((char*)ws + (size_t)(bid ^ 64) * 64);
    uint32_t* obuf32 = (uint32_t*)((char*)ws + 8192) + (size_t)bid * 2048;
    uint32_t* pbuf32 = (uint32_t*)((char*)ws + 8192) + (size_t)(bid ^ 64) * 2048;

    __shared__ __align__(16) short Abuf[2][16 * A_STR]; // ping-pong A tiles
    __shared__ __align__(16) unsigned short wsWl[4096]; // W_out MFMA B-frags
    __shared__ float biasL[512];                        // own 4 gates x 128
    __shared__ __align__(16) float xstage[512];         // x_{t+1} prefetch

    // ---- W_out frags -> LDS ----
    for (int idx = tid; idx < 4096; idx += 256) {
        const int i = idx & 7, lane = (idx >> 3) & 63, kk = idx >> 9;
        const int k = kk * 32 + (lane >> 4) * 8 + i;
        const int n = lane & 15;
        wsWl[idx] = (unsigned short)((n < O_DIM) ? f2bf(W_out[k * O_DIM + n]) : (short)0);
    }
    // ---- bias: own 512 cols, layout [g][128] ----
    #pragma unroll
    for (int e = 0; e < 2; ++e) {
        const int idx = tid + e * 256;
        const int g = idx >> 7, loc = idx & 127;
        biasL[idx] = bvec[g * 256 + hb + loc];
    }

    // ---- register weights: 72 frags = 288 regs (compile-time indexed) ----
    short8 bwx[4][2];       // x chunk (W_ih rows 0..31)
    short8 bwo[4][4][2];    // own-h chunks c=0..3
    short8 bwp[4][4][2];    // partner-h chunks
    #pragma unroll
    for (int g = 0; g < 4; ++g)
        #pragma unroll
        for (int j = 0; j < 2; ++j) {
            const int col = g * 256 + hb + w * 32 + j * 16 + n16;
            {
                short8 f;
                #pragma unroll
                for (int i = 0; i < 8; ++i)
                    f[i] = f2bf(W_ih[(kg * 8 + i) * N4H + col]);
                bwx[g][j] = f;
            }
            #pragma unroll
            for (int c = 0; c < 4; ++c) {
                short8 f, p;
                #pragma unroll
                for (int i = 0; i < 8; ++i) {
                    const int kr = c * 32 + kg * 8 + i;
                    f[i] = f2bf(W_hh[(hb + kr) * N4H + col]);
                    p[i] = f2bf(W_hh[(qb + kr) * N4H + col]);
                }
                bwo[c][g][j] = f;
                bwp[c][g][j] = p;
            }
        }

    const float bout = (w == 0 && n16 < O_DIM) ? b_out[n16] : 0.0f;

    // ---- c state ----
    float creg[2][4];
    #pragma unroll
    for (int j = 0; j < 2; ++j)
        #pragma unroll
        for (int r = 0; r < 4; ++r)
            creg[j][r] = c0[(size_t)(row0 + kg * 4 + r) * H_DIM
                            + (hb + w * 32 + j * 16 + n16)];

    // ---- initial A (buf 0): x_0 + own h0 ----
    #pragma unroll
    for (int e = 0; e < 2; ++e) {
        const int idx = tid + e * 256;
        const int r = idx >> 5, cx = idx & 31;
        Abuf[0][r * A_STR + cx] =
            f2bf(warm[(size_t)(row0 + r) * (T_WARM * F_WARM) + cx]);   // t=0
    }
    #pragma unroll
    for (int e = 0; e < 8; ++e) {
        const int idx = tid + e * 256;
        const int r = idx >> 7, c = idx & 127;
        Abuf[0][r * A_STR + F_WARM + c] = f2bf(h0[(size_t)(row0 + r) * H_DIM + hb + c]);
    }
    // ---- phf init: partner h0 frags ----
    short8 phf[4];
    #pragma unroll
    for (int c = 0; c < 4; ++c) {
        short8 f;
        #pragma unroll
        for (int i = 0; i < 8; ++i)
            f[i] = f2bf(h0[(size_t)(row0 + n16) * H_DIM + qb + c * 32 + kg * 8 + i]);
        phf[c] = f;
    }

    __syncthreads();                            // prologue LDS published
    float bb[2][4];
    #pragma unroll
    for (int j = 0; j < 2; ++j)
        #pragma unroll
        for (int g = 0; g < 4; ++g)
            bb[j][g] = biasL[g * 128 + w * 32 + j * 16 + n16];

    const int aoff = n16 * A_STR + kg * 8;
    short* curp = &Abuf[0][0];
    short* nxtp = &Abuf[1][0];
    const short8* wsW8 = (const short8*)wsWl;
    const int shx = (n16 & 1) * 16;             // row half in u32 word

    for (int t = 0; t < T_TOTAL; ++t) {
        __syncthreads();                        // A_t: buf[t&1] + publishes drained

        if (tid == 0)                           // h_{t-1} readable (drained at A_t)
            __hip_atomic_store(myflag, (uint32_t)t,
                               __ATOMIC_RELAXED, __HIP_MEMORY_SCOPE_SYSTEM);

        // ---- async prefetch x_{t+1} -> xstage ----
        const int tn = t + 1;
        if (tn < T_TOTAL) {
            #pragma unroll
            for (int e = 0; e < 2; ++e) {
                const int idx = tid + e * 256;
                const int r = idx >> 5, cx = idx & 31;
                const float* gp;
                if (tn < T_WARM)
                    gp = &warm[(size_t)(row0 + r) * (T_WARM * F_WARM)
                               + (size_t)tn * F_WARM + cx];
                else
                    gp = &autoin[(size_t)(row0 + r) * (T_WARM * F_AUTO)
                                 + (size_t)(tn - T_WARM) * F_AUTO
                                 + ((cx < F_AUTO) ? cx : 0)];
                __builtin_amdgcn_global_load_lds(
                    (const GLOBAL_AS void*)gp,
                    (LDS_AS void*)&xstage[e * 256 + w * 64], 4, 0, 0);
            }
        }

        // ---- own A-frags from current buffer ----
        const short* ab = curp + aoff;
        short8 afh[4];
        #pragma unroll
        for (int c = 0; c < 4; ++c)
            afh[c] = *(const short8*)(ab + 32 + c * 32);

        // ---- own-chunk MFMAs FIRST (no phf dependency; covers poll) ----
        float4v acc[4][2];
        #pragma unroll
        for (int g = 0; g < 4; ++g)
            #pragma unroll
            for (int j = 0; j < 2; ++j)
                acc[g][j] = (float4v){0.f, 0.f, 0.f, 0.f};
        #pragma unroll
        for (int c = 0; c < 4; ++c)
            #pragma unroll
            for (int g = 0; g < 4; ++g)
                #pragma unroll
                for (int j = 0; j < 2; ++j)
                    acc[g][j] = __builtin_amdgcn_mfma_f32_16x16x32_bf16(
                                    afh[c], bwo[c][g][j], acc[g][j], 0, 0, 0);

        // ---- poll partner flag >= t, then phf loads (h_{t-1}) ----
        if (t >= 1) {
            while (__hip_atomic_load(pflag, __ATOMIC_RELAXED,
                                     __HIP_MEMORY_SCOPE_SYSTEM) < (uint32_t)t)
                __builtin_amdgcn_s_sleep(1);
            asm volatile("" ::: "memory");
            const uint32_t* pb = pbuf32 + ((t - 1) & 1) * 1024;
            #pragma unroll
            for (int c = 0; c < 4; ++c) {
                uint32_t wv[8];
                #pragma unroll
                for (int i = 0; i < 8; ++i)
                    wv[i] = __hip_atomic_load(&pb[(c * 32 + kg * 8 + i) * 8 + (n16 >> 1)],
                                              __ATOMIC_RELAXED, __HIP_MEMORY_SCOPE_SYSTEM);
                short8 f;
                #pragma unroll
                for (int i = 0; i < 8; ++i)
                    f[i] = (short)((wv[i] >> shx) & 0xFFFFu);
                phf[c] = f;
            }
        }

        // ---- partner-chunk MFMAs ----
        #pragma unroll
        for (int c = 0; c < 4; ++c)
            #pragma unroll
            for (int g = 0; g < 4; ++g)
                #pragma unroll
                for (int j = 0; j < 2; ++j)
                    acc[g][j] = __builtin_amdgcn_mfma_f32_16x16x32_bf16(
                                    phf[c], bwp[c][g][j], acc[g][j], 0, 0, 0);

        // ---- wave0: y_{t-1} (skip for half1 during warm: y unused) ----
        if (w == 0 && t >= 1 && (half == 0 || t >= T_WARM)) {
            float4v ya = (float4v){bout, bout, bout, bout};
            #pragma unroll
            for (int c = 0; c < 4; ++c)
                ya = __builtin_amdgcn_mfma_f32_16x16x32_bf16(
                         afh[c], wsW8[(hb / 32 + c) * 64 + l], ya, 0, 0, 0);
            #pragma unroll
            for (int c = 0; c < 4; ++c)
                ya = __builtin_amdgcn_mfma_f32_16x16x32_bf16(
                         phf[c], wsW8[(qb / 32 + c) * 64 + l], ya, 0, 0, 0);
            if (n16 < O_DIM) {
                if (half == 0) {
                    #pragma unroll
                    for (int r = 0; r < 4; ++r)
                        out[(size_t)(row0 + kg * 4 + r) * (T_TOTAL * O_DIM)
                            + (size_t)(t - 1) * O_DIM + n16] = ya[r];
                }
                if (t >= T_WARM) {                      // feedback cols [24,32)
                    #pragma unroll
                    for (int r = 0; r < 4; ++r)
                        curp[(kg * 4 + r) * A_STR + F_AUTO + n16] = f2bf(ya[r]);
                }
            }
        }

        if (t >= T_WARM) __syncthreads();       // B: feedback cols ready

        {
            const short8 af = *(const short8*)(ab);     // x chunk (+feedback)
            #pragma unroll
            for (int g = 0; g < 4; ++g)
                #pragma unroll
                for (int j = 0; j < 2; ++j)
                    acc[g][j] = __builtin_amdgcn_mfma_f32_16x16x32_bf16(
                                    af, bwx[g][j], acc[g][j], 0, 0, 0);
        }

        // ---- gates + c/h update (8 h-vals/thread); HW bf16 pack ----
        uint32_t hp[4];
        #pragma unroll
        for (int j = 0; j < 2; ++j) {
            float hv0, hv1, hv2, hv3;
            #pragma unroll
            for (int r = 0; r < 4; ++r) {
                const float ig = sigmoid_(acc[0][j][r] + bb[j][0]);
                const float fg = sigmoid_(acc[1][j][r] + bb[j][1]);
                const float gg = tanh_(acc[2][j][r] + bb[j][2]);
                const float og = sigmoid_(acc[3][j][r] + bb[j][3]);
                const float cc = fg * creg[j][r] + ig * gg;
                creg[j][r] = cc;
                const float hh = og * tanh_(cc);
                if (r == 0) hv0 = hh; else if (r == 1) hv1 = hh;
                else if (r == 2) hv2 = hh; else hv3 = hh;
            }
            uint32_t u0, u1;
            asm("v_cvt_pk_bf16_f32 %0, %1, %2" : "=v"(u0) : "v"(hv0), "v"(hv1));
            asm("v_cvt_pk_bf16_f32 %0, %1, %2" : "=v"(u1) : "v"(hv2), "v"(hv3));
            hp[j * 2 + 0] = u0;
            hp[j * 2 + 1] = u1;
        }

        // ---- drain x-prefetch loads (issued at step top; was barrier C's job)
        //      BEFORE issuing UC publishes, so this only waits the old loads.
        asm volatile("s_waitcnt vmcnt(0)" ::: "memory");

        // ---- commit prefetched x_{t+1} into NEXT buffer ----
        if (tn < T_TOTAL) {
            #pragma unroll
            for (int e = 0; e < 2; ++e) {
                const int idx = tid + e * 256;
                const int r = idx >> 5, cx = idx & 31;
                if (tn < T_WARM || cx < F_AUTO)
                    nxtp[r * A_STR + cx] = f2bf(xstage[idx]);
            }
        }

        // ---- publish h_t: u32 row-pair words, relaxed system-scope ----
        {
            uint32_t* ob = obuf32 + (t & 1) * 1024;
            #pragma unroll
            for (int j = 0; j < 2; ++j) {
                const int cl = w * 32 + j * 16 + n16;
                __hip_atomic_store(&ob[cl * 8 + kg * 2 + 0], hp[j * 2 + 0],
                                   __ATOMIC_RELAXED, __HIP_MEMORY_SCOPE_SYSTEM);
                __hip_atomic_store(&ob[cl * 8 + kg * 2 + 1], hp[j * 2 + 1],
                                   __ATOMIC_RELAXED, __HIP_MEMORY_SCOPE_SYSTEM);
            }
        }

        // ---- write own h_t into NEXT buffer ----
        #pragma unroll
        for (int j = 0; j < 2; ++j) {
            const int ac = F_WARM + w * 32 + j * 16 + n16;
            const uint32_t u0 = hp[j * 2], u1 = hp[j * 2 + 1];
            nxtp[(kg * 4 + 0) * A_STR + ac] = (short)(u0 & 0xFFFF);
            nxtp[(kg * 4 + 1) * A_STR + ac] = (short)(u0 >> 16);
            nxtp[(kg * 4 + 2) * A_STR + ac] = (short)(u1 & 0xFFFF);
            nxtp[(kg * 4 + 3) * A_STR + ac] = (short)(u1 >> 16);
        }

        { short* tswap = curp; curp = nxtp; nxtp = tswap; }
        // loop-top barrier A_{t+1} drains publishes + ds, publishes buf[(t+1)&1]
    }

    // ---- epilogue: y_{T-1} (wave0; needs partner h_{T-1}) ----
    __syncthreads();                            // drains final publishes
    if (tid == 0)
        __hip_atomic_store(myflag, (uint32_t)T_TOTAL,
                           __ATOMIC_RELAXED, __HIP_MEMORY_SCOPE_SYSTEM);
    if (w == 0) {
        while (__hip_atomic_load(pflag, __ATOMIC_RELAXED,
                                 __HIP_MEMORY_SCOPE_SYSTEM) < (uint32_t)T_TOTAL)
            __builtin_amdgcn_s_sleep(1);
        asm volatile("" ::: "memory");
        const uint32_t* pb = pbuf32 + ((T_TOTAL - 1) & 1) * 1024;
        #pragma unroll
        for (int c = 0; c < 4; ++c) {
            uint32_t wv[8];
            #pragma unroll
            for (int i = 0; i < 8; ++i)
                wv[i] = __hip_atomic_load(&pb[(c * 32 + kg * 8 + i) * 8 + (n16 >> 1)],
                                          __ATOMIC_RELAXED, __HIP_MEMORY_SCOPE_SYSTEM);
            short8 f;
            #pragma unroll
            for (int i = 0; i < 8; ++i)
                f[i] = (short)((wv[i] >> shx) & 0xFFFFu);
            phf[c] = f;
        }
        const short* ab = curp + aoff;          // curp = buf holding h_{T-1}
        float4v ya = (float4v){bout, bout, bout, bout};
        #pragma unroll
        for (int c = 0; c < 4; ++c)
            ya = __builtin_amdgcn_mfma_f32_16x16x32_bf16(
                     *(const short8*)(ab + 32 + c * 32),
                     wsW8[(hb / 32 + c) * 64 + l], ya, 0, 0, 0);
        #pragma unroll
        for (int c = 0; c < 4; ++c)
            ya = __builtin_amdgcn_mfma_f32_16x16x32_bf16(
                     phf[c], wsW8[(qb / 32 + c) * 64 + l], ya, 0, 0, 0);
        if (half == 0 && n16 < O_DIM) {
            #pragma unroll
            for (int r = 0; r < 4; ++r)
                out[(size_t)(row0 + kg * 4 + r) * (T_TOTAL * O_DIM)
                    + (size_t)(T_TOTAL - 1) * O_DIM + n16] = ya[r];
        }
    }
}

extern "C" void kernel_launch(void* const* d_in, const int* in_sizes, int n_in,
                              void* d_out, int out_size, void* d_ws, size_t ws_size,
                              hipStream_t stream) {
    (void)in_sizes; (void)n_in; (void)out_size; (void)ws_size;
    const float* c0   = (const float*)d_in[0];
    const float* h0   = (const float*)d_in[1];
    const float* warm = (const float*)d_in[2];
    const float* aut  = (const float*)d_in[3];
    const float* Wih  = (const float*)d_in[4];
    const float* Whh  = (const float*)d_in[5];
    const float* b    = (const float*)d_in[6];
    const float* Wout = (const float*)d_in[7];
    const float* bout = (const float*)d_in[8];
    float* out = (float*)d_out;
    unsigned short* ws = (unsigned short*)d_ws;
    // ws layout: [0,8KB) flags (64B/WG); [8KB,8KB+1MB) h-exchange ping-pong.
    hipMemsetAsync(d_ws, 0, 8192, stream);
    hipLaunchKernelGGL(lstm_pair, dim3(128), dim3(256), 0, stream,
                       c0, h0, warm, aut, Wih, Whh, b, Wout, bout, out, ws);
}